// Round 2
// baseline (1050.894 us; speedup 1.0000x reference)
//
#include <hip/hip_runtime.h>
#include <math.h>

// Problem dims
#define NB 256
#define NT 512
#define NF 128
#define NCOH 64         // coh_pts
#define NIN 192         // F + coh_pts
#define NBS 384         // 3*bulk_pts
#define NROWS (NB*NT)   // 131072

// Material constants (match fp64->fp32 of reference)
#define C11 1098.9010989010989f
#define C12 329.67032967032966f
#define C33 384.61538461538464f
#define H3G 1253.8461538461538f   // 3*G + HARD

// D-folded fc12 weights: W12p[3p+j][i] = sum_k D[j][k] * W12[3p+k][i]
__device__ float g_W12p[NBS * NIN];

// ---------------------------------------------------------------------------
// K0: fold plane-stress D into W12 (tiny, runs every call; 74K elements)
// ---------------------------------------------------------------------------
__global__ __launch_bounds__(256) void k0_w12(const float* __restrict__ W12)
{
    const int idx = blockIdx.x * 256 + threadIdx.x;   // < 384*192
    const int r = idx / NIN, i = idx - r * NIN;
    const int p = r / 3, j = r - 3 * p;
    const float* w = W12 + (size_t)(3 * p) * NIN;
    float v;
    if (j == 0)      v = C11 * w[i]           + C12 * w[NIN + i];
    else if (j == 1) v = C12 * w[i]           + C11 * w[NIN + i];
    else             v = C33 * w[2 * NIN + i];
    g_W12p[idx] = v;
}

// ---------------------------------------------------------------------------
// K1: jumps = leaky_relu(x @ W11^T + b11); d_new from pairs. Tile 128x128, BK=16.
// ---------------------------------------------------------------------------
__global__ __launch_bounds__(256, 2) void k1_fc11(
    const float* __restrict__ x, const float* __restrict__ W11,
    const float* __restrict__ b11, float* __restrict__ dnew)
{
    __shared__ float As[16][132];
    __shared__ float Bs[16][128];
    const int tid = threadIdx.x;
    const int row0 = blockIdx.x * 128;
    const int tx = tid & 15, ty = tid >> 4;

    float acc[8][8];
#pragma unroll
    for (int i = 0; i < 8; ++i)
#pragma unroll
        for (int j = 0; j < 8; ++j) acc[i][j] = 0.0f;

    const int lr = tid >> 2;          // 0..63
    const int lk = (tid & 3) * 4;     // 0,4,8,12
    const int bn = tid >> 1;          // 0..127
    const int bk = (tid & 1) * 8;     // 0,8

    for (int kc = 0; kc < 8; ++kc) {
        const int k0 = kc * 16;
        float4 a0 = *(const float4*)(x + (size_t)(row0 + lr) * NF + k0 + lk);
        float4 a1 = *(const float4*)(x + (size_t)(row0 + lr + 64) * NF + k0 + lk);
        float4 w0 = *(const float4*)(W11 + (size_t)bn * NF + k0 + bk);
        float4 w1 = *(const float4*)(W11 + (size_t)bn * NF + k0 + bk + 4);
        __syncthreads();
        As[lk+0][lr] = a0.x; As[lk+1][lr] = a0.y; As[lk+2][lr] = a0.z; As[lk+3][lr] = a0.w;
        As[lk+0][lr+64] = a1.x; As[lk+1][lr+64] = a1.y; As[lk+2][lr+64] = a1.z; As[lk+3][lr+64] = a1.w;
        Bs[bk+0][bn] = w0.x; Bs[bk+1][bn] = w0.y; Bs[bk+2][bn] = w0.z; Bs[bk+3][bn] = w0.w;
        Bs[bk+4][bn] = w1.x; Bs[bk+5][bn] = w1.y; Bs[bk+6][bn] = w1.z; Bs[bk+7][bn] = w1.w;
        __syncthreads();
#pragma unroll
        for (int k = 0; k < 16; ++k) {
            float4 av0 = *(const float4*)&As[k][8*ty];
            float4 av1 = *(const float4*)&As[k][8*ty+4];
            float4 bv0 = *(const float4*)&Bs[k][8*tx];
            float4 bv1 = *(const float4*)&Bs[k][8*tx+4];
            float a[8] = {av0.x,av0.y,av0.z,av0.w,av1.x,av1.y,av1.z,av1.w};
            float b[8] = {bv0.x,bv0.y,bv0.z,bv0.w,bv1.x,bv1.y,bv1.z,bv1.w};
#pragma unroll
            for (int i = 0; i < 8; ++i)
#pragma unroll
                for (int j = 0; j < 8; ++j)
                    acc[i][j] = fmaf(a[i], b[j], acc[i][j]);
        }
    }

#pragma unroll
    for (int i = 0; i < 8; ++i) {
        const int row = row0 + 8*ty + i;
        float dnv[4];
#pragma unroll
        for (int jp = 0; jp < 4; ++jp) {
            float z0 = acc[i][2*jp]   + b11[8*tx + 2*jp];
            float z1 = acc[i][2*jp+1] + b11[8*tx + 2*jp+1];
            float jn = fmaxf(z0, 0.0f);
            float js = (z1 > 0.0f) ? z1 : 0.01f * z1;
            float delta = sqrtf(jn*jn + js*js + 1e-12f);
            float dn = 0.1f * (delta - 0.01f) / (fmaxf(delta, 1e-12f) * 0.09f);
            dnv[jp] = fminf(fmaxf(dn, 0.0f), 1.0f);
        }
        float4 dv; dv.x = dnv[0]; dv.y = dnv[1]; dv.z = dnv[2]; dv.w = dnv[3];
        *(float4*)(dnew + (size_t)row * NCOH + 4*tx) = dv;
    }
}

// ---------------------------------------------------------------------------
// K2: in-place cumulative max over t per (b, coh) chain.
// ---------------------------------------------------------------------------
__global__ __launch_bounds__(256) void k2_cummax(float* __restrict__ d)
{
    const int g = blockIdx.x * 256 + threadIdx.x;  // 0..16383
    const int b = g >> 6, c = g & 63;
    float* p = d + (size_t)b * NT * NCOH + c;
    float m = 0.0f;
#pragma unroll 8
    for (int t = 0; t < NT; ++t) {
        float v = p[(size_t)t * NCOH];
        m = fmaxf(m, v);
        p[(size_t)t * NCOH] = m;
    }
}

// ---------------------------------------------------------------------------
// K3: sig_tr = concat(x, dmg) @ W12p^T  (D pre-folded -> trial stress directly)
// Tile 128 rows x 128 cols of 384, BK=16, 12 chunks (8 from x, 4 from dmg).
// ---------------------------------------------------------------------------
__global__ __launch_bounds__(256, 2) void k3_fc12(
    const float* __restrict__ x, const float* __restrict__ dmg,
    float* __restrict__ sig)
{
    __shared__ float As[16][132];
    __shared__ float Bs[16][128];
    const int tid = threadIdx.x;
    const int row0 = blockIdx.x * 128;
    const int n0 = blockIdx.y * 128;
    const int tx = tid & 15, ty = tid >> 4;

    float acc[8][8];
#pragma unroll
    for (int i = 0; i < 8; ++i)
#pragma unroll
        for (int j = 0; j < 8; ++j) acc[i][j] = 0.0f;

    const int lr = tid >> 2;
    const int lk = (tid & 3) * 4;
    const int bn = tid >> 1;
    const int bk = (tid & 1) * 8;

    for (int kc = 0; kc < 12; ++kc) {
        const int k0 = kc * 16;
        float4 a0, a1;
        if (k0 < NF) {
            a0 = *(const float4*)(x + (size_t)(row0 + lr) * NF + k0 + lk);
            a1 = *(const float4*)(x + (size_t)(row0 + lr + 64) * NF + k0 + lk);
        } else {
            a0 = *(const float4*)(dmg + (size_t)(row0 + lr) * NCOH + (k0 - NF) + lk);
            a1 = *(const float4*)(dmg + (size_t)(row0 + lr + 64) * NCOH + (k0 - NF) + lk);
        }
        float4 w0 = *(const float4*)(g_W12p + (size_t)(n0 + bn) * NIN + k0 + bk);
        float4 w1 = *(const float4*)(g_W12p + (size_t)(n0 + bn) * NIN + k0 + bk + 4);
        __syncthreads();
        As[lk+0][lr] = a0.x; As[lk+1][lr] = a0.y; As[lk+2][lr] = a0.z; As[lk+3][lr] = a0.w;
        As[lk+0][lr+64] = a1.x; As[lk+1][lr+64] = a1.y; As[lk+2][lr+64] = a1.z; As[lk+3][lr+64] = a1.w;
        Bs[bk+0][bn] = w0.x; Bs[bk+1][bn] = w0.y; Bs[bk+2][bn] = w0.z; Bs[bk+3][bn] = w0.w;
        Bs[bk+4][bn] = w1.x; Bs[bk+5][bn] = w1.y; Bs[bk+6][bn] = w1.z; Bs[bk+7][bn] = w1.w;
        __syncthreads();
#pragma unroll
        for (int k = 0; k < 16; ++k) {
            float4 av0 = *(const float4*)&As[k][8*ty];
            float4 av1 = *(const float4*)&As[k][8*ty+4];
            float4 bv0 = *(const float4*)&Bs[k][8*tx];
            float4 bv1 = *(const float4*)&Bs[k][8*tx+4];
            float a[8] = {av0.x,av0.y,av0.z,av0.w,av1.x,av1.y,av1.z,av1.w};
            float b[8] = {bv0.x,bv0.y,bv0.z,bv0.w,bv1.x,bv1.y,bv1.z,bv1.w};
#pragma unroll
            for (int i = 0; i < 8; ++i)
#pragma unroll
                for (int j = 0; j < 8; ++j)
                    acc[i][j] = fmaf(a[i], b[j], acc[i][j]);
        }
    }

#pragma unroll
    for (int i = 0; i < 8; ++i) {
        const int row = row0 + 8*ty + i;
        float4 s0, s1;
        s0.x = acc[i][0]; s0.y = acc[i][1]; s0.z = acc[i][2]; s0.w = acc[i][3];
        s1.x = acc[i][4]; s1.y = acc[i][5]; s1.z = acc[i][6]; s1.w = acc[i][7];
        *(float4*)(sig + (size_t)row * NBS + n0 + 8*tx)     = s0;
        *(float4*)(sig + (size_t)row * NBS + n0 + 8*tx + 4) = s1;
    }
}

// ---------------------------------------------------------------------------
// K4 (fused): per-b block (128 threads = 128 chains). Radial-return ep scan +
// fc2 (N=6) reduction + softplus store. Never writes scaled sig back.
// ---------------------------------------------------------------------------
__global__ __launch_bounds__(128) void k4_fused(
    const float* __restrict__ sig, const float* __restrict__ W2,
    float* __restrict__ out)
{
    __shared__ float W2s[6][NBS];      // 9216 B
    __shared__ float red[2][2][6];     // [parity][wave][out]

    const int tid = threadIdx.x;       // 0..127 == chain p
    const int b = blockIdx.x;
    const int lane = tid & 63;
    const int w = tid >> 6;

    for (int i = tid; i < 6 * NBS; i += 128) W2s[i / NBS][i - (i / NBS) * NBS] = W2[i];
    __syncthreads();

    const float* base = sig + (size_t)b * NT * NBS + 3 * tid;
    float* outb = out + (size_t)b * NT * 6;

    // software pipeline, depth 4 (loads independent of ep chain)
    float bx[4], by[4], bz[4];
#pragma unroll
    for (int u = 0; u < 4; ++u) {
        const float* sp = base + (size_t)u * NBS;
        bx[u] = sp[0]; by[u] = sp[1]; bz[u] = sp[2];
    }

    float ep = 0.0f;
#pragma unroll 4
    for (int t = 0; t < NT; ++t) {
        const int s = t & 3;
        float sxx = bx[s], syy = by[s], txy = bz[s];
        if (t + 4 < NT) {
            const float* sp = base + (size_t)(t + 4) * NBS;
            bx[s] = sp[0]; by[s] = sp[1]; bz[s] = sp[2];
        }
        float seq = sqrtf(sxx*sxx - sxx*syy + syy*syy + 3.0f*txy*txy + 1e-12f);
        float fy = seq - (10.0f + 100.0f * ep);
        float dep = (fy > 0.0f) ? (fy / H3G) : 0.0f;
        ep += dep;
        float scale = (fy > 0.0f) ? ((10.0f + 100.0f * ep) / seq) : 1.0f;
        sxx *= scale; syy *= scale; txy *= scale;

        // 6-wide output partials against LDS W2
        float part[6];
#pragma unroll
        for (int o = 0; o < 6; ++o)
            part[o] = sxx * W2s[o][3*tid] + syy * W2s[o][3*tid+1] + txy * W2s[o][3*tid+2];

        // wave butterfly (64 lanes)
#pragma unroll
        for (int o = 0; o < 6; ++o) {
            float v = part[o];
#pragma unroll
            for (int off = 32; off > 0; off >>= 1) v += __shfl_xor(v, off);
            part[o] = v;
        }
        if (lane == 0) {
#pragma unroll
            for (int o = 0; o < 6; ++o) red[t & 1][w][o] = part[o];
        }
        __syncthreads();   // double-buffered red -> one barrier per t is safe
        if (tid < 6) {
            float z = red[t & 1][0][tid] + red[t & 1][1][tid];
            outb[(size_t)t * 6 + tid] = fmaxf(z, 0.0f) + log1pf(expf(-fabsf(z)));
        }
    }
}

// ---------------------------------------------------------------------------
extern "C" void kernel_launch(void* const* d_in, const int* in_sizes, int n_in,
                              void* d_out, int out_size, void* d_ws, size_t ws_size,
                              hipStream_t stream)
{
    const float* x   = (const float*)d_in[0];
    const float* W11 = (const float*)d_in[1];
    const float* b11 = (const float*)d_in[2];
    const float* W12 = (const float*)d_in[3];
    const float* W2  = (const float*)d_in[4];
    float* out = (float*)d_out;

    // ws layout: dnew/dmg [NROWS*64] fp32 (32MB) | sig [NROWS*384] fp32 (192MB)
    float* dnew = (float*)d_ws;
    float* sig  = (float*)((char*)d_ws + (size_t)NROWS * NCOH * sizeof(float));

    k0_w12<<<(NBS * NIN) / 256, 256, 0, stream>>>(W12);
    k1_fc11<<<NROWS / 128, 256, 0, stream>>>(x, W11, b11, dnew);
    k2_cummax<<<(NB * NCOH) / 256, 256, 0, stream>>>(dnew);
    k3_fc12<<<dim3(NROWS / 128, 3), 256, 0, stream>>>(x, dnew, sig);
    k4_fused<<<NB, 128, 0, stream>>>(sig, W2, out);
}

// Round 3
// 684.650 us; speedup vs baseline: 1.5349x; 1.5349x over previous
//
#include <hip/hip_runtime.h>
#include <math.h>

// Problem dims
#define NB 256
#define NT 512
#define NF 128
#define NCOH 64         // coh_pts
#define NIN 192         // F + coh_pts
#define NBS 384         // 3*bulk_pts
#define NROWS (NB*NT)   // 131072

// Material constants (match fp64->fp32 of reference)
#define C11 1098.9010989010989f
#define C12 329.67032967032966f
#define C33 384.61538461538464f
#define H3G 1253.8461538461538f   // 3*G + HARD

// D-folded fc12 weights: W12p[3p+j][i] = sum_k D[j][k] * W12[3p+k][i]
__device__ float g_W12p[NBS * NIN];

// ---------------------------------------------------------------------------
// K0: fold plane-stress D into W12 (tiny; validated R2: absmax unchanged)
// ---------------------------------------------------------------------------
__global__ __launch_bounds__(256) void k0_w12(const float* __restrict__ W12)
{
    const int idx = blockIdx.x * 256 + threadIdx.x;   // < 384*192
    const int r = idx / NIN, i = idx - r * NIN;
    const int p = r / 3, j = r - 3 * p;
    const float* w = W12 + (size_t)(3 * p) * NIN;
    float v;
    if (j == 0)      v = C11 * w[i]           + C12 * w[NIN + i];
    else if (j == 1) v = C12 * w[i]           + C11 * w[NIN + i];
    else             v = C33 * w[2 * NIN + i];
    g_W12p[idx] = v;
}

// ---------------------------------------------------------------------------
// K1: jumps = leaky_relu(x @ W11^T + b11); d_new from pairs. Tile 128x128, BK=16.
// ---------------------------------------------------------------------------
__global__ __launch_bounds__(256, 2) void k1_fc11(
    const float* __restrict__ x, const float* __restrict__ W11,
    const float* __restrict__ b11, float* __restrict__ dnew)
{
    __shared__ float As[16][132];
    __shared__ float Bs[16][128];
    const int tid = threadIdx.x;
    const int row0 = blockIdx.x * 128;
    const int tx = tid & 15, ty = tid >> 4;

    float acc[8][8];
#pragma unroll
    for (int i = 0; i < 8; ++i)
#pragma unroll
        for (int j = 0; j < 8; ++j) acc[i][j] = 0.0f;

    const int lr = tid >> 2;          // 0..63
    const int lk = (tid & 3) * 4;     // 0,4,8,12
    const int bn = tid >> 1;          // 0..127
    const int bk = (tid & 1) * 8;     // 0,8

    for (int kc = 0; kc < 8; ++kc) {
        const int k0 = kc * 16;
        float4 a0 = *(const float4*)(x + (size_t)(row0 + lr) * NF + k0 + lk);
        float4 a1 = *(const float4*)(x + (size_t)(row0 + lr + 64) * NF + k0 + lk);
        float4 w0 = *(const float4*)(W11 + (size_t)bn * NF + k0 + bk);
        float4 w1 = *(const float4*)(W11 + (size_t)bn * NF + k0 + bk + 4);
        __syncthreads();
        As[lk+0][lr] = a0.x; As[lk+1][lr] = a0.y; As[lk+2][lr] = a0.z; As[lk+3][lr] = a0.w;
        As[lk+0][lr+64] = a1.x; As[lk+1][lr+64] = a1.y; As[lk+2][lr+64] = a1.z; As[lk+3][lr+64] = a1.w;
        Bs[bk+0][bn] = w0.x; Bs[bk+1][bn] = w0.y; Bs[bk+2][bn] = w0.z; Bs[bk+3][bn] = w0.w;
        Bs[bk+4][bn] = w1.x; Bs[bk+5][bn] = w1.y; Bs[bk+6][bn] = w1.z; Bs[bk+7][bn] = w1.w;
        __syncthreads();
#pragma unroll
        for (int k = 0; k < 16; ++k) {
            float4 av0 = *(const float4*)&As[k][8*ty];
            float4 av1 = *(const float4*)&As[k][8*ty+4];
            float4 bv0 = *(const float4*)&Bs[k][8*tx];
            float4 bv1 = *(const float4*)&Bs[k][8*tx+4];
            float a[8] = {av0.x,av0.y,av0.z,av0.w,av1.x,av1.y,av1.z,av1.w};
            float b[8] = {bv0.x,bv0.y,bv0.z,bv0.w,bv1.x,bv1.y,bv1.z,bv1.w};
#pragma unroll
            for (int i = 0; i < 8; ++i)
#pragma unroll
                for (int j = 0; j < 8; ++j)
                    acc[i][j] = fmaf(a[i], b[j], acc[i][j]);
        }
    }

#pragma unroll
    for (int i = 0; i < 8; ++i) {
        const int row = row0 + 8*ty + i;
        float dnv[4];
#pragma unroll
        for (int jp = 0; jp < 4; ++jp) {
            float z0 = acc[i][2*jp]   + b11[8*tx + 2*jp];
            float z1 = acc[i][2*jp+1] + b11[8*tx + 2*jp+1];
            float jn = fmaxf(z0, 0.0f);
            float js = (z1 > 0.0f) ? z1 : 0.01f * z1;
            float delta = sqrtf(jn*jn + js*js + 1e-12f);
            float dn = 0.1f * (delta - 0.01f) / (fmaxf(delta, 1e-12f) * 0.09f);
            dnv[jp] = fminf(fmaxf(dn, 0.0f), 1.0f);
        }
        float4 dv; dv.x = dnv[0]; dv.y = dnv[1]; dv.z = dnv[2]; dv.w = dnv[3];
        *(float4*)(dnew + (size_t)row * NCOH + 4*tx) = dv;
    }
}

// ---------------------------------------------------------------------------
// K2: in-place cumulative max over t. 256 blocks x 64 threads = all CUs busy;
// depth-8 register prefetch (loads independent of the max chain).
// ---------------------------------------------------------------------------
__global__ __launch_bounds__(64) void k2_cummax(float* __restrict__ d)
{
    const int b = blockIdx.x;          // one batch per block
    const int c = threadIdx.x;         // 0..63
    float* p = d + (size_t)b * NT * NCOH + c;

    float buf[8];
#pragma unroll
    for (int u = 0; u < 8; ++u) buf[u] = p[(size_t)u * NCOH];

    float m = 0.0f;
#pragma unroll 8
    for (int t = 0; t < NT - 8; ++t) {
        const int sl = t & 7;
        float v = buf[sl];
        buf[sl] = p[(size_t)(t + 8) * NCOH];
        m = fmaxf(m, v);
        p[(size_t)t * NCOH] = m;
    }
#pragma unroll
    for (int t = NT - 8; t < NT; ++t) {
        m = fmaxf(m, buf[t & 7]);
        p[(size_t)t * NCOH] = m;
    }
}

// ---------------------------------------------------------------------------
// K3: sig_tr = concat(x, dmg) @ W12p^T  (D pre-folded -> trial stress directly)
// ---------------------------------------------------------------------------
__global__ __launch_bounds__(256, 2) void k3_fc12(
    const float* __restrict__ x, const float* __restrict__ dmg,
    float* __restrict__ sig)
{
    __shared__ float As[16][132];
    __shared__ float Bs[16][128];
    const int tid = threadIdx.x;
    const int row0 = blockIdx.x * 128;
    const int n0 = blockIdx.y * 128;
    const int tx = tid & 15, ty = tid >> 4;

    float acc[8][8];
#pragma unroll
    for (int i = 0; i < 8; ++i)
#pragma unroll
        for (int j = 0; j < 8; ++j) acc[i][j] = 0.0f;

    const int lr = tid >> 2;
    const int lk = (tid & 3) * 4;
    const int bn = tid >> 1;
    const int bk = (tid & 1) * 8;

    for (int kc = 0; kc < 12; ++kc) {
        const int k0 = kc * 16;
        float4 a0, a1;
        if (k0 < NF) {
            a0 = *(const float4*)(x + (size_t)(row0 + lr) * NF + k0 + lk);
            a1 = *(const float4*)(x + (size_t)(row0 + lr + 64) * NF + k0 + lk);
        } else {
            a0 = *(const float4*)(dmg + (size_t)(row0 + lr) * NCOH + (k0 - NF) + lk);
            a1 = *(const float4*)(dmg + (size_t)(row0 + lr + 64) * NCOH + (k0 - NF) + lk);
        }
        float4 w0 = *(const float4*)(g_W12p + (size_t)(n0 + bn) * NIN + k0 + bk);
        float4 w1 = *(const float4*)(g_W12p + (size_t)(n0 + bn) * NIN + k0 + bk + 4);
        __syncthreads();
        As[lk+0][lr] = a0.x; As[lk+1][lr] = a0.y; As[lk+2][lr] = a0.z; As[lk+3][lr] = a0.w;
        As[lk+0][lr+64] = a1.x; As[lk+1][lr+64] = a1.y; As[lk+2][lr+64] = a1.z; As[lk+3][lr+64] = a1.w;
        Bs[bk+0][bn] = w0.x; Bs[bk+1][bn] = w0.y; Bs[bk+2][bn] = w0.z; Bs[bk+3][bn] = w0.w;
        Bs[bk+4][bn] = w1.x; Bs[bk+5][bn] = w1.y; Bs[bk+6][bn] = w1.z; Bs[bk+7][bn] = w1.w;
        __syncthreads();
#pragma unroll
        for (int k = 0; k < 16; ++k) {
            float4 av0 = *(const float4*)&As[k][8*ty];
            float4 av1 = *(const float4*)&As[k][8*ty+4];
            float4 bv0 = *(const float4*)&Bs[k][8*tx];
            float4 bv1 = *(const float4*)&Bs[k][8*tx+4];
            float a[8] = {av0.x,av0.y,av0.z,av0.w,av1.x,av1.y,av1.z,av1.w};
            float b[8] = {bv0.x,bv0.y,bv0.z,bv0.w,bv1.x,bv1.y,bv1.z,bv1.w};
#pragma unroll
            for (int i = 0; i < 8; ++i)
#pragma unroll
                for (int j = 0; j < 8; ++j)
                    acc[i][j] = fmaf(a[i], b[j], acc[i][j]);
        }
    }

#pragma unroll
    for (int i = 0; i < 8; ++i) {
        const int row = row0 + 8*ty + i;
        float4 s0, s1;
        s0.x = acc[i][0]; s0.y = acc[i][1]; s0.z = acc[i][2]; s0.w = acc[i][3];
        s1.x = acc[i][4]; s1.y = acc[i][5]; s1.z = acc[i][6]; s1.w = acc[i][7];
        *(float4*)(sig + (size_t)row * NBS + n0 + 8*tx)     = s0;
        *(float4*)(sig + (size_t)row * NBS + n0 + 8*tx + 4) = s1;
    }
}

// ---------------------------------------------------------------------------
// K4: radial-return ep scan, scaled stress written back in place.
// 256 blocks x 128 threads = all CUs; depth-8 circular register prefetch
// (loads are off the ep dependence chain -> ~6 KB/wave in flight).
// No cross-lane ops, no barriers (R2 lesson).
// ---------------------------------------------------------------------------
__global__ __launch_bounds__(128) void k4_plast(float* __restrict__ sig)
{
    const int b = blockIdx.x;          // one batch per block
    const int p = threadIdx.x;         // 0..127 chain
    float* s = sig + (size_t)b * NT * NBS + 3 * p;

    float px[8], py[8], pz[8];
#pragma unroll
    for (int u = 0; u < 8; ++u) {
        const float* sp = s + (size_t)u * NBS;
        px[u] = sp[0]; py[u] = sp[1]; pz[u] = sp[2];
    }

    float ep = 0.0f;
#pragma unroll 8
    for (int t = 0; t < NT - 8; ++t) {
        const int sl = t & 7;
        float sxx = px[sl], syy = py[sl], txy = pz[sl];
        {   // prefetch t+8 into the freed slot
            const float* sp = s + (size_t)(t + 8) * NBS;
            px[sl] = sp[0]; py[sl] = sp[1]; pz[sl] = sp[2];
        }
        float seq = sqrtf(sxx*sxx - sxx*syy + syy*syy + 3.0f*txy*txy + 1e-12f);
        float fy = seq - (10.0f + 100.0f * ep);
        float dep = (fy > 0.0f) ? (fy / H3G) : 0.0f;
        ep += dep;
        float scale = (fy > 0.0f) ? ((10.0f + 100.0f * ep) / seq) : 1.0f;
        float* op = s + (size_t)t * NBS;
        op[0] = sxx * scale; op[1] = syy * scale; op[2] = txy * scale;
    }
#pragma unroll
    for (int t = NT - 8; t < NT; ++t) {
        const int sl = t & 7;
        float sxx = px[sl], syy = py[sl], txy = pz[sl];
        float seq = sqrtf(sxx*sxx - sxx*syy + syy*syy + 3.0f*txy*txy + 1e-12f);
        float fy = seq - (10.0f + 100.0f * ep);
        float dep = (fy > 0.0f) ? (fy / H3G) : 0.0f;
        ep += dep;
        float scale = (fy > 0.0f) ? ((10.0f + 100.0f * ep) / seq) : 1.0f;
        float* op = s + (size_t)t * NBS;
        op[0] = sxx * scale; op[1] = syy * scale; op[2] = txy * scale;
    }
}

// ---------------------------------------------------------------------------
// K5: out = softplus(sig @ W2^T), wave-per-row, W2 in LDS. 2048 blocks ->
// 8192 waves = 32 waves/CU, barrier-free per row.
// ---------------------------------------------------------------------------
__global__ __launch_bounds__(256) void k5_out(
    const float* __restrict__ sig, const float* __restrict__ W2,
    float* __restrict__ out)
{
    __shared__ float W2s[6][NBS];
    const int tid = threadIdx.x;
    for (int i = tid; i < 6 * NBS; i += 256) W2s[i / NBS][i % NBS] = W2[i];
    __syncthreads();

    const int lane = tid & 63;
    const int wid = (blockIdx.x * 256 + tid) >> 6;
    const int nw = (gridDim.x * 256) >> 6;
    for (int row = wid; row < NROWS; row += nw) {
        const float* s = sig + (size_t)row * NBS;
        float acc[6] = {0,0,0,0,0,0};
#pragma unroll
        for (int kk = 0; kk < 6; ++kk) {
            float v = s[lane + 64*kk];
#pragma unroll
            for (int o = 0; o < 6; ++o) acc[o] = fmaf(v, W2s[o][lane + 64*kk], acc[o]);
        }
#pragma unroll
        for (int o = 0; o < 6; ++o) {
#pragma unroll
            for (int off = 32; off > 0; off >>= 1)
                acc[o] += __shfl_xor(acc[o], off);
        }
        if (lane == 0) {
#pragma unroll
            for (int o = 0; o < 6; ++o) {
                float z = acc[o];
                out[(size_t)row * 6 + o] = fmaxf(z, 0.0f) + log1pf(expf(-fabsf(z)));
            }
        }
    }
}

// ---------------------------------------------------------------------------
extern "C" void kernel_launch(void* const* d_in, const int* in_sizes, int n_in,
                              void* d_out, int out_size, void* d_ws, size_t ws_size,
                              hipStream_t stream)
{
    const float* x   = (const float*)d_in[0];
    const float* W11 = (const float*)d_in[1];
    const float* b11 = (const float*)d_in[2];
    const float* W12 = (const float*)d_in[3];
    const float* W2  = (const float*)d_in[4];
    float* out = (float*)d_out;

    // ws layout: dnew/dmg [NROWS*64] fp32 (32MB) | sig [NROWS*384] fp32 (192MB)
    float* dnew = (float*)d_ws;
    float* sig  = (float*)((char*)d_ws + (size_t)NROWS * NCOH * sizeof(float));

    k0_w12<<<(NBS * NIN) / 256, 256, 0, stream>>>(W12);
    k1_fc11<<<NROWS / 128, 256, 0, stream>>>(x, W11, b11, dnew);
    k2_cummax<<<NB, 64, 0, stream>>>(dnew);
    k3_fc12<<<dim3(NROWS / 128, 3), 256, 0, stream>>>(x, dnew, sig);
    k4_plast<<<NB, 128, 0, stream>>>(sig);
    k5_out<<<2048, 256, 0, stream>>>(sig, W2, out);
}

// Round 4
// 626.686 us; speedup vs baseline: 1.6769x; 1.0925x over previous
//
#include <hip/hip_runtime.h>
#include <hip/hip_bf16.h>
#include <math.h>

// Problem dims
#define NB 256
#define NT 512
#define NF 128
#define NCOH 64         // coh_pts
#define NIN 192         // F + coh_pts
#define NBS 384         // 3*bulk_pts
#define NROWS (NB*NT)   // 131072

// Material constants (match fp64->fp32 of reference)
#define C11 1098.9010989010989f
#define C12 329.67032967032966f
#define C33 384.61538461538464f
#define H3G 1253.8461538461538f   // 3*G + HARD

typedef __attribute__((ext_vector_type(8))) short bf16x8;   // 8 bf16 = 4 VGPR
typedef __attribute__((ext_vector_type(4))) float f32x4;    // MFMA acc
typedef __attribute__((ext_vector_type(4))) short short4v;

// bf16 hi/lo split operands (rewritten in full every call -> no stale state)
__device__ unsigned short g_Ahi[(size_t)NROWS * NIN];   // concat(x, dmg) hi
__device__ unsigned short g_Alo[(size_t)NROWS * NIN];   // concat(x, dmg) lo
__device__ unsigned short g_Bhi[NBS * NIN];             // D-folded W12 hi
__device__ unsigned short g_Blo[NBS * NIN];             // D-folded W12 lo

static __device__ __forceinline__ unsigned short f2bf(float v) {
    __hip_bfloat16 h = __float2bfloat16(v);
    return *reinterpret_cast<unsigned short*>(&h);
}
static __device__ __forceinline__ float bf2f(unsigned short u) {
    __hip_bfloat16 h; *reinterpret_cast<unsigned short*>(&h) = u;
    return __bfloat162float(h);
}
static __device__ __forceinline__ void async_copy16(const void* g, void* l) {
    __builtin_amdgcn_global_load_lds(
        (const __attribute__((address_space(1))) unsigned int*)g,
        (__attribute__((address_space(3))) unsigned int*)l, 16, 0, 0);
}

// ---------------------------------------------------------------------------
// K0: fold plane-stress D into W12 and split to bf16 hi/lo.
// ---------------------------------------------------------------------------
__global__ __launch_bounds__(256) void k0_w12(const float* __restrict__ W12)
{
    const int idx = blockIdx.x * 256 + threadIdx.x;   // < 384*192 = 73728
    const int r = idx / NIN, i = idx - r * NIN;
    const int p = r / 3, j = r - 3 * p;
    const float* w = W12 + (size_t)(3 * p) * NIN;
    float v;
    if (j == 0)      v = C11 * w[i]           + C12 * w[NIN + i];
    else if (j == 1) v = C12 * w[i]           + C11 * w[NIN + i];
    else             v = C33 * w[2 * NIN + i];
    unsigned short h = f2bf(v);
    g_Bhi[idx] = h;
    g_Blo[idx] = f2bf(v - bf2f(h));
}

// ---------------------------------------------------------------------------
// KX: split x (fp32) into bf16 hi/lo -> cols 0..127 of the A operand buffers.
// ---------------------------------------------------------------------------
__global__ __launch_bounds__(256) void kx_split(const float* __restrict__ x)
{
    const int idx = blockIdx.x * 256 + threadIdx.x;   // NROWS*32
    const int row = idx >> 5, c4 = (idx & 31) * 4;
    float4 v = *(const float4*)(x + (size_t)row * NF + c4);
    float vv[4] = {v.x, v.y, v.z, v.w};
    short4v hv, lv;
#pragma unroll
    for (int i = 0; i < 4; ++i) {
        unsigned short h = f2bf(vv[i]);
        hv[i] = (short)h;
        lv[i] = (short)f2bf(vv[i] - bf2f(h));
    }
    const size_t o = (size_t)row * NIN + c4;
    *(short4v*)(g_Ahi + o) = hv;
    *(short4v*)(g_Alo + o) = lv;
}

// ---------------------------------------------------------------------------
// K1: jumps = leaky_relu(x @ W11^T + b11); d_new from pairs. fp32, unchanged.
// ---------------------------------------------------------------------------
__global__ __launch_bounds__(256, 2) void k1_fc11(
    const float* __restrict__ x, const float* __restrict__ W11,
    const float* __restrict__ b11, float* __restrict__ dnew)
{
    __shared__ float As[16][132];
    __shared__ float Bs[16][128];
    const int tid = threadIdx.x;
    const int row0 = blockIdx.x * 128;
    const int tx = tid & 15, ty = tid >> 4;

    float acc[8][8];
#pragma unroll
    for (int i = 0; i < 8; ++i)
#pragma unroll
        for (int j = 0; j < 8; ++j) acc[i][j] = 0.0f;

    const int lr = tid >> 2;
    const int lk = (tid & 3) * 4;
    const int bn = tid >> 1;
    const int bk = (tid & 1) * 8;

    for (int kc = 0; kc < 8; ++kc) {
        const int k0 = kc * 16;
        float4 a0 = *(const float4*)(x + (size_t)(row0 + lr) * NF + k0 + lk);
        float4 a1 = *(const float4*)(x + (size_t)(row0 + lr + 64) * NF + k0 + lk);
        float4 w0 = *(const float4*)(W11 + (size_t)bn * NF + k0 + bk);
        float4 w1 = *(const float4*)(W11 + (size_t)bn * NF + k0 + bk + 4);
        __syncthreads();
        As[lk+0][lr] = a0.x; As[lk+1][lr] = a0.y; As[lk+2][lr] = a0.z; As[lk+3][lr] = a0.w;
        As[lk+0][lr+64] = a1.x; As[lk+1][lr+64] = a1.y; As[lk+2][lr+64] = a1.z; As[lk+3][lr+64] = a1.w;
        Bs[bk+0][bn] = w0.x; Bs[bk+1][bn] = w0.y; Bs[bk+2][bn] = w0.z; Bs[bk+3][bn] = w0.w;
        Bs[bk+4][bn] = w1.x; Bs[bk+5][bn] = w1.y; Bs[bk+6][bn] = w1.z; Bs[bk+7][bn] = w1.w;
        __syncthreads();
#pragma unroll
        for (int k = 0; k < 16; ++k) {
            float4 av0 = *(const float4*)&As[k][8*ty];
            float4 av1 = *(const float4*)&As[k][8*ty+4];
            float4 bv0 = *(const float4*)&Bs[k][8*tx];
            float4 bv1 = *(const float4*)&Bs[k][8*tx+4];
            float a[8] = {av0.x,av0.y,av0.z,av0.w,av1.x,av1.y,av1.z,av1.w};
            float b[8] = {bv0.x,bv0.y,bv0.z,bv0.w,bv1.x,bv1.y,bv1.z,bv1.w};
#pragma unroll
            for (int i = 0; i < 8; ++i)
#pragma unroll
                for (int j = 0; j < 8; ++j)
                    acc[i][j] = fmaf(a[i], b[j], acc[i][j]);
        }
    }

#pragma unroll
    for (int i = 0; i < 8; ++i) {
        const int row = row0 + 8*ty + i;
        float dnv[4];
#pragma unroll
        for (int jp = 0; jp < 4; ++jp) {
            float z0 = acc[i][2*jp]   + b11[8*tx + 2*jp];
            float z1 = acc[i][2*jp+1] + b11[8*tx + 2*jp+1];
            float jn = fmaxf(z0, 0.0f);
            float js = (z1 > 0.0f) ? z1 : 0.01f * z1;
            float delta = sqrtf(jn*jn + js*js + 1e-12f);
            float dn = 0.1f * (delta - 0.01f) / (fmaxf(delta, 1e-12f) * 0.09f);
            dnv[jp] = fminf(fmaxf(dn, 0.0f), 1.0f);
        }
        float4 dv; dv.x = dnv[0]; dv.y = dnv[1]; dv.z = dnv[2]; dv.w = dnv[3];
        *(float4*)(dnew + (size_t)row * NCOH + 4*tx) = dv;
    }
}

// ---------------------------------------------------------------------------
// K2: cummax over t; emit dmg as bf16 hi/lo into cols 128..191 of A buffers.
// ---------------------------------------------------------------------------
__global__ __launch_bounds__(64) void k2_cummax(const float* __restrict__ d)
{
    const int b = blockIdx.x;          // one batch per block
    const int c = threadIdx.x;         // 0..63
    const float* p = d + (size_t)b * NT * NCOH + c;
    unsigned short* ah = g_Ahi + (size_t)b * NT * NIN + NF + c;
    unsigned short* al = g_Alo + (size_t)b * NT * NIN + NF + c;

    float buf[8];
#pragma unroll
    for (int u = 0; u < 8; ++u) buf[u] = p[(size_t)u * NCOH];

    float m = 0.0f;
#pragma unroll 8
    for (int t = 0; t < NT - 8; ++t) {
        const int sl = t & 7;
        float v = buf[sl];
        buf[sl] = p[(size_t)(t + 8) * NCOH];
        m = fmaxf(m, v);
        unsigned short h = f2bf(m);
        ah[(size_t)t * NIN] = h;
        al[(size_t)t * NIN] = f2bf(m - bf2f(h));
    }
#pragma unroll
    for (int t = NT - 8; t < NT; ++t) {
        m = fmaxf(m, buf[t & 7]);
        unsigned short h = f2bf(m);
        ah[(size_t)t * NIN] = h;
        al[(size_t)t * NIN] = f2bf(m - bf2f(h));
    }
}

// ---------------------------------------------------------------------------
// K3: sig_tr = A @ B^T via bf16x3 MFMA: Ahi*Bhi + Ahi*Blo + Alo*Bhi.
// 128x128 tile, BK=32, 2x2 waves of 64x64, global_load_lds width-16 staging.
// K-loop = 3 segments x 6 chunks = 18.
// ---------------------------------------------------------------------------
__global__ __launch_bounds__(256) void k3_mfma(float* __restrict__ sig)
{
    __shared__ unsigned short As[128 * 32];   // [row][k], 64 B/row
    __shared__ unsigned short Bs[128 * 32];

    const int tid = threadIdx.x;
    const int lane = tid & 63, w = tid >> 6;
    const int m0 = blockIdx.y * 128;
    const int n0 = blockIdx.x * 128;          // x fastest: 3 n-tiles share A rows (L2/L3 reuse)
    const int wm = (w >> 1) * 64, wn = (w & 1) * 64;
    const int fr = lane & 15, fq = lane >> 4;

    f32x4 acc[4][4];
#pragma unroll
    for (int mi = 0; mi < 4; ++mi)
#pragma unroll
        for (int ni = 0; ni < 4; ++ni) acc[mi][ni] = (f32x4){0.f, 0.f, 0.f, 0.f};

    // staging geometry: wave w stages bytes [(w*2+j)*1024, +1024) as base+lane*16
    const int offA0 = (w * 2 + 0) * 1024 + lane * 16;
    const int offA1 = (w * 2 + 1) * 1024 + lane * 16;
    const int rA0 = offA0 >> 6, qA0 = (offA0 >> 4) & 3;
    const int rA1 = offA1 >> 6, qA1 = (offA1 >> 4) & 3;

    const unsigned short* Asegs[3] = {g_Ahi, g_Ahi, g_Alo};
    const unsigned short* Bsegs[3] = {g_Bhi, g_Blo, g_Bhi};

    for (int seg = 0; seg < 3; ++seg) {
        const unsigned short* Ag = Asegs[seg];
        const unsigned short* Bg = Bsegs[seg];
        for (int kc = 0; kc < 6; ++kc) {
            const int kb = kc * 32;
            __syncthreads();   // previous chunk's reads done before overwrite
            async_copy16(Ag + (size_t)(m0 + rA0) * NIN + kb + qA0 * 8, (char*)As + offA0);
            async_copy16(Ag + (size_t)(m0 + rA1) * NIN + kb + qA1 * 8, (char*)As + offA1);
            async_copy16(Bg + (size_t)(n0 + rA0) * NIN + kb + qA0 * 8, (char*)Bs + offA0);
            async_copy16(Bg + (size_t)(n0 + rA1) * NIN + kb + qA1 * 8, (char*)Bs + offA1);
            __syncthreads();   // drains vmcnt (global_load_lds) per barrier semantics

            bf16x8 a[4], b[4];
#pragma unroll
            for (int mi = 0; mi < 4; ++mi)
                a[mi] = *(bf16x8*)&As[(wm + mi * 16 + fr) * 32 + fq * 8];
#pragma unroll
            for (int ni = 0; ni < 4; ++ni)
                b[ni] = *(bf16x8*)&Bs[(wn + ni * 16 + fr) * 32 + fq * 8];
#pragma unroll
            for (int mi = 0; mi < 4; ++mi)
#pragma unroll
                for (int ni = 0; ni < 4; ++ni)
                    acc[mi][ni] = __builtin_amdgcn_mfma_f32_16x16x32_bf16(
                        a[mi], b[ni], acc[mi][ni], 0, 0, 0);
        }
    }

    // epilogue: C/D layout col=lane&15, row=(lane>>4)*4+reg  [m89-verified]
    const int er = fq * 4, ec = fr;
#pragma unroll
    for (int mi = 0; mi < 4; ++mi)
#pragma unroll
        for (int ni = 0; ni < 4; ++ni)
#pragma unroll
            for (int r = 0; r < 4; ++r)
                sig[(size_t)(m0 + wm + mi * 16 + er + r) * NBS + (n0 + wn + ni * 16 + ec)]
                    = acc[mi][ni][r];
}

// ---------------------------------------------------------------------------
// K4: radial-return ep scan, scaled stress written back in place.
// depth-16 circular register prefetch: 24 KB/CU in flight (Little's law match).
// ---------------------------------------------------------------------------
__global__ __launch_bounds__(128) void k4_plast(float* __restrict__ sig)
{
    const int b = blockIdx.x;          // one batch per block
    const int p = threadIdx.x;         // 0..127 chain
    float* s = sig + (size_t)b * NT * NBS + 3 * p;

    float px[16], py[16], pz[16];
#pragma unroll
    for (int u = 0; u < 16; ++u) {
        const float* sp = s + (size_t)u * NBS;
        px[u] = sp[0]; py[u] = sp[1]; pz[u] = sp[2];
    }

    float ep = 0.0f;
#pragma unroll 16
    for (int t = 0; t < NT - 16; ++t) {
        const int sl = t & 15;
        float sxx = px[sl], syy = py[sl], txy = pz[sl];
        {   // prefetch t+16 into the freed slot
            const float* sp = s + (size_t)(t + 16) * NBS;
            px[sl] = sp[0]; py[sl] = sp[1]; pz[sl] = sp[2];
        }
        float seq = sqrtf(sxx*sxx - sxx*syy + syy*syy + 3.0f*txy*txy + 1e-12f);
        float fy = seq - (10.0f + 100.0f * ep);
        float dep = (fy > 0.0f) ? (fy / H3G) : 0.0f;
        ep += dep;
        float scale = (fy > 0.0f) ? ((10.0f + 100.0f * ep) / seq) : 1.0f;
        float* op = s + (size_t)t * NBS;
        op[0] = sxx * scale; op[1] = syy * scale; op[2] = txy * scale;
    }
#pragma unroll
    for (int t = NT - 16; t < NT; ++t) {
        const int sl = t & 15;
        float sxx = px[sl], syy = py[sl], txy = pz[sl];
        float seq = sqrtf(sxx*sxx - sxx*syy + syy*syy + 3.0f*txy*txy + 1e-12f);
        float fy = seq - (10.0f + 100.0f * ep);
        float dep = (fy > 0.0f) ? (fy / H3G) : 0.0f;
        ep += dep;
        float scale = (fy > 0.0f) ? ((10.0f + 100.0f * ep) / seq) : 1.0f;
        float* op = s + (size_t)t * NBS;
        op[0] = sxx * scale; op[1] = syy * scale; op[2] = txy * scale;
    }
}

// ---------------------------------------------------------------------------
// K5: out = softplus(sig @ W2^T), wave-per-row, W2 in LDS, barrier-free.
// ---------------------------------------------------------------------------
__global__ __launch_bounds__(256) void k5_out(
    const float* __restrict__ sig, const float* __restrict__ W2,
    float* __restrict__ out)
{
    __shared__ float W2s[6][NBS];
    const int tid = threadIdx.x;
    for (int i = tid; i < 6 * NBS; i += 256) W2s[i / NBS][i % NBS] = W2[i];
    __syncthreads();

    const int lane = tid & 63;
    const int wid = (blockIdx.x * 256 + tid) >> 6;
    const int nw = (gridDim.x * 256) >> 6;
    for (int row = wid; row < NROWS; row += nw) {
        const float* s = sig + (size_t)row * NBS;
        float acc[6] = {0,0,0,0,0,0};
#pragma unroll
        for (int kk = 0; kk < 6; ++kk) {
            float v = s[lane + 64*kk];
#pragma unroll
            for (int o = 0; o < 6; ++o) acc[o] = fmaf(v, W2s[o][lane + 64*kk], acc[o]);
        }
#pragma unroll
        for (int o = 0; o < 6; ++o) {
#pragma unroll
            for (int off = 32; off > 0; off >>= 1)
                acc[o] += __shfl_xor(acc[o], off);
        }
        if (lane == 0) {
#pragma unroll
            for (int o = 0; o < 6; ++o) {
                float z = acc[o];
                out[(size_t)row * 6 + o] = fmaxf(z, 0.0f) + log1pf(expf(-fabsf(z)));
            }
        }
    }
}

// ---------------------------------------------------------------------------
extern "C" void kernel_launch(void* const* d_in, const int* in_sizes, int n_in,
                              void* d_out, int out_size, void* d_ws, size_t ws_size,
                              hipStream_t stream)
{
    const float* x   = (const float*)d_in[0];
    const float* W11 = (const float*)d_in[1];
    const float* b11 = (const float*)d_in[2];
    const float* W12 = (const float*)d_in[3];
    const float* W2  = (const float*)d_in[4];
    float* out = (float*)d_out;

    // ws layout: dnew [NROWS*64] fp32 (32MB) | sig [NROWS*384] fp32 (192MB)
    float* dnew = (float*)d_ws;
    float* sig  = (float*)((char*)d_ws + (size_t)NROWS * NCOH * sizeof(float));

    k0_w12<<<(NBS * NIN) / 256, 256, 0, stream>>>(W12);
    kx_split<<<(NROWS * 32) / 256, 256, 0, stream>>>(x);
    k1_fc11<<<NROWS / 128, 256, 0, stream>>>(x, W11, b11, dnew);
    k2_cummax<<<NB, 64, 0, stream>>>(dnew);
    k3_mfma<<<dim3(3, NROWS / 128), 256, 0, stream>>>(sig);
    k4_plast<<<NB, 128, 0, stream>>>(sig);
    k5_out<<<2048, 256, 0, stream>>>(sig, W2, out);
}

// Round 5
// 515.621 us; speedup vs baseline: 2.0381x; 1.2154x over previous
//
#include <hip/hip_runtime.h>
#include <hip/hip_bf16.h>
#include <math.h>

// Problem dims
#define NB 256
#define NT 512
#define NF 128
#define NCOH 64         // coh_pts
#define NIN 192         // F + coh_pts
#define NBS 384         // 3*bulk_pts
#define NROWS (NB*NT)   // 131072

// Material constants (match fp64->fp32 of reference)
#define C11 1098.9010989010989f
#define C12 329.67032967032966f
#define C33 384.61538461538464f
#define H3G 1253.8461538461538f   // 3*G + HARD

typedef __attribute__((ext_vector_type(8))) short bf16x8;   // 8 bf16 = 4 VGPR
typedef __attribute__((ext_vector_type(4))) float f32x4;    // MFMA acc
typedef __attribute__((ext_vector_type(4))) short short4v;

// bf16 hi/lo split operands (rewritten in full every call -> no stale state)
__device__ unsigned short g_Ahi[(size_t)NROWS * NIN];   // concat(x, dmg) hi
__device__ unsigned short g_Alo[(size_t)NROWS * NIN];   // concat(x, dmg) lo
__device__ unsigned short g_Bhi[NBS * NIN];             // D-folded W12 hi
__device__ unsigned short g_Blo[NBS * NIN];             // D-folded W12 lo

static __device__ __forceinline__ unsigned short f2bf(float v) {
    __hip_bfloat16 h = __float2bfloat16(v);
    return *reinterpret_cast<unsigned short*>(&h);
}
static __device__ __forceinline__ float bf2f(unsigned short u) {
    __hip_bfloat16 h; *reinterpret_cast<unsigned short*>(&h) = u;
    return __bfloat162float(h);
}
static __device__ __forceinline__ void async_copy16(const void* g, void* l) {
    __builtin_amdgcn_global_load_lds(
        (const __attribute__((address_space(1))) unsigned int*)g,
        (__attribute__((address_space(3))) unsigned int*)l, 16, 0, 0);
}

// ---------------------------------------------------------------------------
// K0: fold plane-stress D into W12 and split to bf16 hi/lo.
// ---------------------------------------------------------------------------
__global__ __launch_bounds__(256) void k0_w12(const float* __restrict__ W12)
{
    const int idx = blockIdx.x * 256 + threadIdx.x;   // < 384*192 = 73728
    const int r = idx / NIN, i = idx - r * NIN;
    const int p = r / 3, j = r - 3 * p;
    const float* w = W12 + (size_t)(3 * p) * NIN;
    float v;
    if (j == 0)      v = C11 * w[i]           + C12 * w[NIN + i];
    else if (j == 1) v = C12 * w[i]           + C11 * w[NIN + i];
    else             v = C33 * w[2 * NIN + i];
    unsigned short h = f2bf(v);
    g_Bhi[idx] = h;
    g_Blo[idx] = f2bf(v - bf2f(h));
}

// ---------------------------------------------------------------------------
// KX: split x (fp32) into bf16 hi/lo -> cols 0..127 of the A operand buffers.
// ---------------------------------------------------------------------------
__global__ __launch_bounds__(256) void kx_split(const float* __restrict__ x)
{
    const int idx = blockIdx.x * 256 + threadIdx.x;   // NROWS*32
    const int row = idx >> 5, c4 = (idx & 31) * 4;
    float4 v = *(const float4*)(x + (size_t)row * NF + c4);
    float vv[4] = {v.x, v.y, v.z, v.w};
    short4v hv, lv;
#pragma unroll
    for (int i = 0; i < 4; ++i) {
        unsigned short h = f2bf(vv[i]);
        hv[i] = (short)h;
        lv[i] = (short)f2bf(vv[i] - bf2f(h));
    }
    const size_t o = (size_t)row * NIN + c4;
    *(short4v*)(g_Ahi + o) = hv;
    *(short4v*)(g_Alo + o) = lv;
}

// ---------------------------------------------------------------------------
// K1: jumps = leaky_relu(x @ W11^T + b11); d_new from pairs. fp32, unchanged.
// ---------------------------------------------------------------------------
__global__ __launch_bounds__(256, 2) void k1_fc11(
    const float* __restrict__ x, const float* __restrict__ W11,
    const float* __restrict__ b11, float* __restrict__ dnew)
{
    __shared__ float As[16][132];
    __shared__ float Bs[16][128];
    const int tid = threadIdx.x;
    const int row0 = blockIdx.x * 128;
    const int tx = tid & 15, ty = tid >> 4;

    float acc[8][8];
#pragma unroll
    for (int i = 0; i < 8; ++i)
#pragma unroll
        for (int j = 0; j < 8; ++j) acc[i][j] = 0.0f;

    const int lr = tid >> 2;
    const int lk = (tid & 3) * 4;
    const int bn = tid >> 1;
    const int bk = (tid & 1) * 8;

    for (int kc = 0; kc < 8; ++kc) {
        const int k0 = kc * 16;
        float4 a0 = *(const float4*)(x + (size_t)(row0 + lr) * NF + k0 + lk);
        float4 a1 = *(const float4*)(x + (size_t)(row0 + lr + 64) * NF + k0 + lk);
        float4 w0 = *(const float4*)(W11 + (size_t)bn * NF + k0 + bk);
        float4 w1 = *(const float4*)(W11 + (size_t)bn * NF + k0 + bk + 4);
        __syncthreads();
        As[lk+0][lr] = a0.x; As[lk+1][lr] = a0.y; As[lk+2][lr] = a0.z; As[lk+3][lr] = a0.w;
        As[lk+0][lr+64] = a1.x; As[lk+1][lr+64] = a1.y; As[lk+2][lr+64] = a1.z; As[lk+3][lr+64] = a1.w;
        Bs[bk+0][bn] = w0.x; Bs[bk+1][bn] = w0.y; Bs[bk+2][bn] = w0.z; Bs[bk+3][bn] = w0.w;
        Bs[bk+4][bn] = w1.x; Bs[bk+5][bn] = w1.y; Bs[bk+6][bn] = w1.z; Bs[bk+7][bn] = w1.w;
        __syncthreads();
#pragma unroll
        for (int k = 0; k < 16; ++k) {
            float4 av0 = *(const float4*)&As[k][8*ty];
            float4 av1 = *(const float4*)&As[k][8*ty+4];
            float4 bv0 = *(const float4*)&Bs[k][8*tx];
            float4 bv1 = *(const float4*)&Bs[k][8*tx+4];
            float a[8] = {av0.x,av0.y,av0.z,av0.w,av1.x,av1.y,av1.z,av1.w};
            float b[8] = {bv0.x,bv0.y,bv0.z,bv0.w,bv1.x,bv1.y,bv1.z,bv1.w};
#pragma unroll
            for (int i = 0; i < 8; ++i)
#pragma unroll
                for (int j = 0; j < 8; ++j)
                    acc[i][j] = fmaf(a[i], b[j], acc[i][j]);
        }
    }

#pragma unroll
    for (int i = 0; i < 8; ++i) {
        const int row = row0 + 8*ty + i;
        float dnv[4];
#pragma unroll
        for (int jp = 0; jp < 4; ++jp) {
            float z0 = acc[i][2*jp]   + b11[8*tx + 2*jp];
            float z1 = acc[i][2*jp+1] + b11[8*tx + 2*jp+1];
            float jn = fmaxf(z0, 0.0f);
            float js = (z1 > 0.0f) ? z1 : 0.01f * z1;
            float delta = sqrtf(jn*jn + js*js + 1e-12f);
            float dn = 0.1f * (delta - 0.01f) / (fmaxf(delta, 1e-12f) * 0.09f);
            dnv[jp] = fminf(fmaxf(dn, 0.0f), 1.0f);
        }
        float4 dv; dv.x = dnv[0]; dv.y = dnv[1]; dv.z = dnv[2]; dv.w = dnv[3];
        *(float4*)(dnew + (size_t)row * NCOH + 4*tx) = dv;
    }
}

// ---------------------------------------------------------------------------
// K2: cummax over t; emit dmg as bf16 hi/lo into cols 128..191 of A buffers.
// ---------------------------------------------------------------------------
__global__ __launch_bounds__(64) void k2_cummax(const float* __restrict__ d)
{
    const int b = blockIdx.x;          // one batch per block
    const int c = threadIdx.x;         // 0..63
    const float* p = d + (size_t)b * NT * NCOH + c;
    unsigned short* ah = g_Ahi + (size_t)b * NT * NIN + NF + c;
    unsigned short* al = g_Alo + (size_t)b * NT * NIN + NF + c;

    float buf[8];
#pragma unroll
    for (int u = 0; u < 8; ++u) buf[u] = p[(size_t)u * NCOH];

    float m = 0.0f;
#pragma unroll 8
    for (int t = 0; t < NT - 8; ++t) {
        const int sl = t & 7;
        float v = buf[sl];
        buf[sl] = p[(size_t)(t + 8) * NCOH];
        m = fmaxf(m, v);
        unsigned short h = f2bf(m);
        ah[(size_t)t * NIN] = h;
        al[(size_t)t * NIN] = f2bf(m - bf2f(h));
    }
#pragma unroll
    for (int t = NT - 8; t < NT; ++t) {
        m = fmaxf(m, buf[t & 7]);
        unsigned short h = f2bf(m);
        ah[(size_t)t * NIN] = h;
        al[(size_t)t * NIN] = f2bf(m - bf2f(h));
    }
}

// ---------------------------------------------------------------------------
// K3: sig_tr = A @ B^T via bf16x3 MFMA: Ahi*Bhi + Ahi*Blo + Alo*Bhi.
// 128x128 tile, BK=32, 2x2 waves of 64x64, global_load_lds width-16 staging.
// ---------------------------------------------------------------------------
__global__ __launch_bounds__(256) void k3_mfma(float* __restrict__ sig)
{
    __shared__ unsigned short As[128 * 32];   // [row][k], 64 B/row
    __shared__ unsigned short Bs[128 * 32];

    const int tid = threadIdx.x;
    const int lane = tid & 63, w = tid >> 6;
    const int m0 = blockIdx.y * 128;
    const int n0 = blockIdx.x * 128;          // x fastest: 3 n-tiles share A rows
    const int wm = (w >> 1) * 64, wn = (w & 1) * 64;
    const int fr = lane & 15, fq = lane >> 4;

    f32x4 acc[4][4];
#pragma unroll
    for (int mi = 0; mi < 4; ++mi)
#pragma unroll
        for (int ni = 0; ni < 4; ++ni) acc[mi][ni] = (f32x4){0.f, 0.f, 0.f, 0.f};

    const int offA0 = (w * 2 + 0) * 1024 + lane * 16;
    const int offA1 = (w * 2 + 1) * 1024 + lane * 16;
    const int rA0 = offA0 >> 6, qA0 = (offA0 >> 4) & 3;
    const int rA1 = offA1 >> 6, qA1 = (offA1 >> 4) & 3;

    const unsigned short* Asegs[3] = {g_Ahi, g_Ahi, g_Alo};
    const unsigned short* Bsegs[3] = {g_Bhi, g_Blo, g_Bhi};

    for (int seg = 0; seg < 3; ++seg) {
        const unsigned short* Ag = Asegs[seg];
        const unsigned short* Bg = Bsegs[seg];
        for (int kc = 0; kc < 6; ++kc) {
            const int kb = kc * 32;
            __syncthreads();
            async_copy16(Ag + (size_t)(m0 + rA0) * NIN + kb + qA0 * 8, (char*)As + offA0);
            async_copy16(Ag + (size_t)(m0 + rA1) * NIN + kb + qA1 * 8, (char*)As + offA1);
            async_copy16(Bg + (size_t)(n0 + rA0) * NIN + kb + qA0 * 8, (char*)Bs + offA0);
            async_copy16(Bg + (size_t)(n0 + rA1) * NIN + kb + qA1 * 8, (char*)Bs + offA1);
            __syncthreads();

            bf16x8 a[4], b[4];
#pragma unroll
            for (int mi = 0; mi < 4; ++mi)
                a[mi] = *(bf16x8*)&As[(wm + mi * 16 + fr) * 32 + fq * 8];
#pragma unroll
            for (int ni = 0; ni < 4; ++ni)
                b[ni] = *(bf16x8*)&Bs[(wn + ni * 16 + fr) * 32 + fq * 8];
#pragma unroll
            for (int mi = 0; mi < 4; ++mi)
#pragma unroll
                for (int ni = 0; ni < 4; ++ni)
                    acc[mi][ni] = __builtin_amdgcn_mfma_f32_16x16x32_bf16(
                        a[mi], b[ni], acc[mi][ni], 0, 0, 0);
        }
    }

    // epilogue: C/D layout col=lane&15, row=(lane>>4)*4+reg  [m89-verified]
    const int er = fq * 4, ec = fr;
#pragma unroll
    for (int mi = 0; mi < 4; ++mi)
#pragma unroll
        for (int ni = 0; ni < 4; ++ni)
#pragma unroll
            for (int r = 0; r < 4; ++r)
                sig[(size_t)(m0 + wm + mi * 16 + er + r) * NBS + (n0 + wn + ni * 16 + ec)]
                    = acc[mi][ni][r];
}

// ---------------------------------------------------------------------------
// K4: radial-return ep scan, scaled stress written back in place.
// depth-16 circular register prefetch.
// ---------------------------------------------------------------------------
__global__ __launch_bounds__(128) void k4_plast(float* __restrict__ sig)
{
    const int b = blockIdx.x;          // one batch per block
    const int p = threadIdx.x;         // 0..127 chain
    float* s = sig + (size_t)b * NT * NBS + 3 * p;

    float px[16], py[16], pz[16];
#pragma unroll
    for (int u = 0; u < 16; ++u) {
        const float* sp = s + (size_t)u * NBS;
        px[u] = sp[0]; py[u] = sp[1]; pz[u] = sp[2];
    }

    float ep = 0.0f;
#pragma unroll 16
    for (int t = 0; t < NT - 16; ++t) {
        const int sl = t & 15;
        float sxx = px[sl], syy = py[sl], txy = pz[sl];
        {
            const float* sp = s + (size_t)(t + 16) * NBS;
            px[sl] = sp[0]; py[sl] = sp[1]; pz[sl] = sp[2];
        }
        float seq = sqrtf(sxx*sxx - sxx*syy + syy*syy + 3.0f*txy*txy + 1e-12f);
        float fy = seq - (10.0f + 100.0f * ep);
        float dep = (fy > 0.0f) ? (fy / H3G) : 0.0f;
        ep += dep;
        float scale = (fy > 0.0f) ? ((10.0f + 100.0f * ep) / seq) : 1.0f;
        float* op = s + (size_t)t * NBS;
        op[0] = sxx * scale; op[1] = syy * scale; op[2] = txy * scale;
    }
#pragma unroll
    for (int t = NT - 16; t < NT; ++t) {
        const int sl = t & 15;
        float sxx = px[sl], syy = py[sl], txy = pz[sl];
        float seq = sqrtf(sxx*sxx - sxx*syy + syy*syy + 3.0f*txy*txy + 1e-12f);
        float fy = seq - (10.0f + 100.0f * ep);
        float dep = (fy > 0.0f) ? (fy / H3G) : 0.0f;
        ep += dep;
        float scale = (fy > 0.0f) ? ((10.0f + 100.0f * ep) / seq) : 1.0f;
        float* op = s + (size_t)t * NBS;
        op[0] = sxx * scale; op[1] = syy * scale; op[2] = txy * scale;
    }
}

// ---------------------------------------------------------------------------
// K5: out = softplus(sig @ W2^T). Row-per-THREAD, zero cross-lane ops
// (R4 lesson: the 36-deep shuffle chain per row was the bottleneck, not FMAs).
// W2 broadcast from LDS (same-address -> bank broadcast, conflict-free);
// 96 independent float4 loads of the row pipeline freely.
// ---------------------------------------------------------------------------
__global__ __launch_bounds__(256) void k5_out(
    const float* __restrict__ sig, const float* __restrict__ W2,
    float* __restrict__ out)
{
    __shared__ float W2s[6][NBS];
    const int tid = threadIdx.x;
    for (int i = tid; i < 6 * NBS; i += 256) W2s[i / NBS][i % NBS] = W2[i];
    __syncthreads();

    const int row = blockIdx.x * 256 + tid;     // 512 blocks x 256 = NROWS
    const float4* sv = (const float4*)(sig + (size_t)row * NBS);

    float acc[6] = {0, 0, 0, 0, 0, 0};
#pragma unroll 8
    for (int q = 0; q < NBS / 4; ++q) {
        float4 v = sv[q];
#pragma unroll
        for (int o = 0; o < 6; ++o) {
            float4 wv = *(const float4*)&W2s[o][4 * q];
            acc[o] = fmaf(v.x, wv.x, acc[o]);
            acc[o] = fmaf(v.y, wv.y, acc[o]);
            acc[o] = fmaf(v.z, wv.z, acc[o]);
            acc[o] = fmaf(v.w, wv.w, acc[o]);
        }
    }

    float res[6];
#pragma unroll
    for (int o = 0; o < 6; ++o) {
        float z = acc[o];
        res[o] = fmaxf(z, 0.0f) + log1pf(expf(-fabsf(z)));
    }
    float* op = out + (size_t)row * 6;
#pragma unroll
    for (int o = 0; o < 6; ++o) op[o] = res[o];
}

// ---------------------------------------------------------------------------
extern "C" void kernel_launch(void* const* d_in, const int* in_sizes, int n_in,
                              void* d_out, int out_size, void* d_ws, size_t ws_size,
                              hipStream_t stream)
{
    const float* x   = (const float*)d_in[0];
    const float* W11 = (const float*)d_in[1];
    const float* b11 = (const float*)d_in[2];
    const float* W12 = (const float*)d_in[3];
    const float* W2  = (const float*)d_in[4];
    float* out = (float*)d_out;

    // ws layout: dnew [NROWS*64] fp32 (32MB) | sig [NROWS*384] fp32 (192MB)
    float* dnew = (float*)d_ws;
    float* sig  = (float*)((char*)d_ws + (size_t)NROWS * NCOH * sizeof(float));

    k0_w12<<<(NBS * NIN) / 256, 256, 0, stream>>>(W12);
    kx_split<<<(NROWS * 32) / 256, 256, 0, stream>>>(x);
    k1_fc11<<<NROWS / 128, 256, 0, stream>>>(x, W11, b11, dnew);
    k2_cummax<<<NB, 64, 0, stream>>>(dnew);
    k3_mfma<<<dim3(3, NROWS / 128), 256, 0, stream>>>(sig);
    k4_plast<<<NB, 128, 0, stream>>>(sig);
    k5_out<<<NROWS / 256, 256, 0, stream>>>(sig, W2, out);
}

// Round 6
// 514.740 us; speedup vs baseline: 2.0416x; 1.0017x over previous
//
#include <hip/hip_runtime.h>
#include <hip/hip_bf16.h>
#include <math.h>

// Problem dims
#define NB 256
#define NT 512
#define NF 128
#define NCOH 64         // coh_pts
#define NIN 192         // F + coh_pts
#define NBS 384         // 3*bulk_pts
#define NROWS (NB*NT)   // 131072

// Material constants (match fp64->fp32 of reference)
#define C11 1098.9010989010989f
#define C12 329.67032967032966f
#define C33 384.61538461538464f
#define H3G 1253.8461538461538f   // 3*G + HARD

typedef __attribute__((ext_vector_type(8))) short bf16x8;   // 8 bf16 = 4 VGPR
typedef __attribute__((ext_vector_type(4))) float f32x4;    // MFMA acc
typedef __attribute__((ext_vector_type(4))) short short4v;

// s_waitcnt with only vmcnt constrained (expcnt=7, lgkmcnt=15 = no-wait)
#define WAITCNT_VM(N) __builtin_amdgcn_s_waitcnt(0x0F70 | ((N) & 15) | (((N) >> 4) << 14))

// bf16 hi/lo split operands (rewritten in full every call -> no stale state)
__device__ unsigned short g_Ahi[(size_t)NROWS * NIN];   // concat(x, dmg) hi
__device__ unsigned short g_Alo[(size_t)NROWS * NIN];   // concat(x, dmg) lo
__device__ unsigned short g_Bhi[NBS * NIN];             // D-folded W12 hi
__device__ unsigned short g_Blo[NBS * NIN];             // D-folded W12 lo

static __device__ __forceinline__ unsigned short f2bf(float v) {
    __hip_bfloat16 h = __float2bfloat16(v);
    return *reinterpret_cast<unsigned short*>(&h);
}
static __device__ __forceinline__ float bf2f(unsigned short u) {
    __hip_bfloat16 h; *reinterpret_cast<unsigned short*>(&h) = u;
    return __bfloat162float(h);
}
static __device__ __forceinline__ void async_copy16(const void* g, void* l) {
    __builtin_amdgcn_global_load_lds(
        (const __attribute__((address_space(1))) unsigned int*)g,
        (__attribute__((address_space(3))) unsigned int*)l, 16, 0, 0);
}

// ---------------------------------------------------------------------------
// K0: fold plane-stress D into W12 and split to bf16 hi/lo.
// ---------------------------------------------------------------------------
__global__ __launch_bounds__(256) void k0_w12(const float* __restrict__ W12)
{
    const int idx = blockIdx.x * 256 + threadIdx.x;   // < 384*192 = 73728
    const int r = idx / NIN, i = idx - r * NIN;
    const int p = r / 3, j = r - 3 * p;
    const float* w = W12 + (size_t)(3 * p) * NIN;
    float v;
    if (j == 0)      v = C11 * w[i]           + C12 * w[NIN + i];
    else if (j == 1) v = C12 * w[i]           + C11 * w[NIN + i];
    else             v = C33 * w[2 * NIN + i];
    unsigned short h = f2bf(v);
    g_Bhi[idx] = h;
    g_Blo[idx] = f2bf(v - bf2f(h));
}

// ---------------------------------------------------------------------------
// KX: split x (fp32) into bf16 hi/lo -> cols 0..127 of the A operand buffers.
// ---------------------------------------------------------------------------
__global__ __launch_bounds__(256) void kx_split(const float* __restrict__ x)
{
    const int idx = blockIdx.x * 256 + threadIdx.x;   // NROWS*32
    const int row = idx >> 5, c4 = (idx & 31) * 4;
    float4 v = *(const float4*)(x + (size_t)row * NF + c4);
    float vv[4] = {v.x, v.y, v.z, v.w};
    short4v hv, lv;
#pragma unroll
    for (int i = 0; i < 4; ++i) {
        unsigned short h = f2bf(vv[i]);
        hv[i] = (short)h;
        lv[i] = (short)f2bf(vv[i] - bf2f(h));
    }
    const size_t o = (size_t)row * NIN + c4;
    *(short4v*)(g_Ahi + o) = hv;
    *(short4v*)(g_Alo + o) = lv;
}

// ---------------------------------------------------------------------------
// K1: jumps = leaky_relu(x @ W11^T + b11); d_new from pairs. fp32, unchanged.
// ---------------------------------------------------------------------------
__global__ __launch_bounds__(256, 2) void k1_fc11(
    const float* __restrict__ x, const float* __restrict__ W11,
    const float* __restrict__ b11, float* __restrict__ dnew)
{
    __shared__ float As[16][132];
    __shared__ float Bs[16][128];
    const int tid = threadIdx.x;
    const int row0 = blockIdx.x * 128;
    const int tx = tid & 15, ty = tid >> 4;

    float acc[8][8];
#pragma unroll
    for (int i = 0; i < 8; ++i)
#pragma unroll
        for (int j = 0; j < 8; ++j) acc[i][j] = 0.0f;

    const int lr = tid >> 2;
    const int lk = (tid & 3) * 4;
    const int bn = tid >> 1;
    const int bk = (tid & 1) * 8;

    for (int kc = 0; kc < 8; ++kc) {
        const int k0 = kc * 16;
        float4 a0 = *(const float4*)(x + (size_t)(row0 + lr) * NF + k0 + lk);
        float4 a1 = *(const float4*)(x + (size_t)(row0 + lr + 64) * NF + k0 + lk);
        float4 w0 = *(const float4*)(W11 + (size_t)bn * NF + k0 + bk);
        float4 w1 = *(const float4*)(W11 + (size_t)bn * NF + k0 + bk + 4);
        __syncthreads();
        As[lk+0][lr] = a0.x; As[lk+1][lr] = a0.y; As[lk+2][lr] = a0.z; As[lk+3][lr] = a0.w;
        As[lk+0][lr+64] = a1.x; As[lk+1][lr+64] = a1.y; As[lk+2][lr+64] = a1.z; As[lk+3][lr+64] = a1.w;
        Bs[bk+0][bn] = w0.x; Bs[bk+1][bn] = w0.y; Bs[bk+2][bn] = w0.z; Bs[bk+3][bn] = w0.w;
        Bs[bk+4][bn] = w1.x; Bs[bk+5][bn] = w1.y; Bs[bk+6][bn] = w1.z; Bs[bk+7][bn] = w1.w;
        __syncthreads();
#pragma unroll
        for (int k = 0; k < 16; ++k) {
            float4 av0 = *(const float4*)&As[k][8*ty];
            float4 av1 = *(const float4*)&As[k][8*ty+4];
            float4 bv0 = *(const float4*)&Bs[k][8*tx];
            float4 bv1 = *(const float4*)&Bs[k][8*tx+4];
            float a[8] = {av0.x,av0.y,av0.z,av0.w,av1.x,av1.y,av1.z,av1.w};
            float b[8] = {bv0.x,bv0.y,bv0.z,bv0.w,bv1.x,bv1.y,bv1.z,bv1.w};
#pragma unroll
            for (int i = 0; i < 8; ++i)
#pragma unroll
                for (int j = 0; j < 8; ++j)
                    acc[i][j] = fmaf(a[i], b[j], acc[i][j]);
        }
    }

#pragma unroll
    for (int i = 0; i < 8; ++i) {
        const int row = row0 + 8*ty + i;
        float dnv[4];
#pragma unroll
        for (int jp = 0; jp < 4; ++jp) {
            float z0 = acc[i][2*jp]   + b11[8*tx + 2*jp];
            float z1 = acc[i][2*jp+1] + b11[8*tx + 2*jp+1];
            float jn = fmaxf(z0, 0.0f);
            float js = (z1 > 0.0f) ? z1 : 0.01f * z1;
            float delta = sqrtf(jn*jn + js*js + 1e-12f);
            float dn = 0.1f * (delta - 0.01f) / (fmaxf(delta, 1e-12f) * 0.09f);
            dnv[jp] = fminf(fmaxf(dn, 0.0f), 1.0f);
        }
        float4 dv; dv.x = dnv[0]; dv.y = dnv[1]; dv.z = dnv[2]; dv.w = dnv[3];
        *(float4*)(dnew + (size_t)row * NCOH + 4*tx) = dv;
    }
}

// ---------------------------------------------------------------------------
// K2: cummax over t; emit dmg as bf16 hi/lo into cols 128..191 of A buffers.
// ---------------------------------------------------------------------------
__global__ __launch_bounds__(64) void k2_cummax(const float* __restrict__ d)
{
    const int b = blockIdx.x;          // one batch per block
    const int c = threadIdx.x;         // 0..63
    const float* p = d + (size_t)b * NT * NCOH + c;
    unsigned short* ah = g_Ahi + (size_t)b * NT * NIN + NF + c;
    unsigned short* al = g_Alo + (size_t)b * NT * NIN + NF + c;

    float buf[8];
#pragma unroll
    for (int u = 0; u < 8; ++u) buf[u] = p[(size_t)u * NCOH];

    float m = 0.0f;
#pragma unroll 8
    for (int t = 0; t < NT - 8; ++t) {
        const int sl = t & 7;
        float v = buf[sl];
        buf[sl] = p[(size_t)(t + 8) * NCOH];
        m = fmaxf(m, v);
        unsigned short h = f2bf(m);
        ah[(size_t)t * NIN] = h;
        al[(size_t)t * NIN] = f2bf(m - bf2f(h));
    }
#pragma unroll
    for (int t = NT - 8; t < NT; ++t) {
        m = fmaxf(m, buf[t & 7]);
        unsigned short h = f2bf(m);
        ah[(size_t)t * NIN] = h;
        al[(size_t)t * NIN] = f2bf(m - bf2f(h));
    }
}

// ---------------------------------------------------------------------------
// K3: sig_tr = A @ B^T via bf16x3 MFMA (Ahi*Bhi + Ahi*Blo + Alo*Bhi = K=576).
// R6: AITER-style software pipeline — triple-buffered LDS chunks, prefetch
// 1 ahead with global_load_lds, raw s_waitcnt vmcnt(4) + raw s_barrier,
// ONE barrier per chunk, vmcnt never drained to 0 until the last chunk.
// Triple-buffer invariant: prefetch target (c+1)%3 is 2 mod 3 away from
// the buffer any lagging wave can still be reading ((c-1)%3).
// ---------------------------------------------------------------------------
__global__ __launch_bounds__(256) void k3_mfma(float* __restrict__ sig)
{
    __shared__ unsigned short As[3][128 * 32];   // 3 x 8 KB
    __shared__ unsigned short Bs[3][128 * 32];   // 3 x 8 KB

    const int tid = threadIdx.x;
    const int lane = tid & 63, w = tid >> 6;
    const int m0 = blockIdx.y * 128;
    const int n0 = blockIdx.x * 128;          // x fastest: 3 n-tiles share A rows
    const int wm = (w >> 1) * 64, wn = (w & 1) * 64;
    const int fr = lane & 15, fq = lane >> 4;

    f32x4 acc[4][4];
#pragma unroll
    for (int mi = 0; mi < 4; ++mi)
#pragma unroll
        for (int ni = 0; ni < 4; ++ni) acc[mi][ni] = (f32x4){0.f, 0.f, 0.f, 0.f};

    // staging: 8 KB per operand chunk / 256 threads = 2 x 16 B per thread
    const int off0 = tid * 16;            // bytes in [0, 4096)
    const int off1 = tid * 16 + 4096;     // bytes in [4096, 8192)
    const int r0 = off0 >> 6, q0 = (off0 >> 4) & 3;
    const int r1 = off1 >> 6, q1 = (off1 >> 4) & 3;

    const unsigned short* Aseg[3] = {g_Ahi, g_Ahi, g_Alo};
    const unsigned short* Bseg[3] = {g_Bhi, g_Blo, g_Bhi};

    // chunk schedule: c = 0..17 -> seg = c/6, kb = (c%6)*32 (tracked incrementally)
    int seg_n = 0, kb_n = 0;   // of the NEXT chunk to issue

    // issue chunk 0 into buf 0
    {
        const unsigned short* Ag = Aseg[0];
        const unsigned short* Bg = Bseg[0];
        async_copy16(Ag + (size_t)(m0 + r0) * NIN + q0 * 8, (char*)As[0] + off0);
        async_copy16(Ag + (size_t)(m0 + r1) * NIN + q1 * 8, (char*)As[0] + off1);
        async_copy16(Bg + (size_t)(n0 + r0) * NIN + q0 * 8, (char*)Bs[0] + off0);
        async_copy16(Bg + (size_t)(n0 + r1) * NIN + q1 * 8, (char*)Bs[0] + off1);
        kb_n = 32;
    }

    int buf = 0;
#pragma unroll 1
    for (int c = 0; c < 17; ++c) {
        // prefetch chunk c+1 into buf (c+1)%3
        const int nbuf = (buf == 2) ? 0 : buf + 1;
        {
            const unsigned short* Ag = Aseg[seg_n];
            const unsigned short* Bg = Bseg[seg_n];
            async_copy16(Ag + (size_t)(m0 + r0) * NIN + kb_n + q0 * 8, (char*)As[nbuf] + off0);
            async_copy16(Ag + (size_t)(m0 + r1) * NIN + kb_n + q1 * 8, (char*)As[nbuf] + off1);
            async_copy16(Bg + (size_t)(n0 + r0) * NIN + kb_n + q0 * 8, (char*)Bs[nbuf] + off0);
            async_copy16(Bg + (size_t)(n0 + r1) * NIN + kb_n + q1 * 8, (char*)Bs[nbuf] + off1);
            kb_n += 32;
            if (kb_n == NIN) { kb_n = 0; ++seg_n; }
        }
        WAITCNT_VM(4);                       // own chunk-c copies landed
        __builtin_amdgcn_s_barrier();        // everyone's chunk-c landed

        bf16x8 a[4], b[4];
#pragma unroll
        for (int mi = 0; mi < 4; ++mi)
            a[mi] = *(bf16x8*)&As[buf][(wm + mi * 16 + fr) * 32 + fq * 8];
#pragma unroll
        for (int ni = 0; ni < 4; ++ni)
            b[ni] = *(bf16x8*)&Bs[buf][(wn + ni * 16 + fr) * 32 + fq * 8];
#pragma unroll
        for (int mi = 0; mi < 4; ++mi)
#pragma unroll
            for (int ni = 0; ni < 4; ++ni)
                acc[mi][ni] = __builtin_amdgcn_mfma_f32_16x16x32_bf16(
                    a[mi], b[ni], acc[mi][ni], 0, 0, 0);
        buf = nbuf;
    }

    // last chunk (c = 17), buf = 17%3 = 2
    WAITCNT_VM(0);
    __builtin_amdgcn_s_barrier();
    {
        bf16x8 a[4], b[4];
#pragma unroll
        for (int mi = 0; mi < 4; ++mi)
            a[mi] = *(bf16x8*)&As[buf][(wm + mi * 16 + fr) * 32 + fq * 8];
#pragma unroll
        for (int ni = 0; ni < 4; ++ni)
            b[ni] = *(bf16x8*)&Bs[buf][(wn + ni * 16 + fr) * 32 + fq * 8];
#pragma unroll
        for (int mi = 0; mi < 4; ++mi)
#pragma unroll
            for (int ni = 0; ni < 4; ++ni)
                acc[mi][ni] = __builtin_amdgcn_mfma_f32_16x16x32_bf16(
                    a[mi], b[ni], acc[mi][ni], 0, 0, 0);
    }

    // epilogue: C/D layout col=lane&15, row=(lane>>4)*4+reg  [m89-verified]
    const int er = fq * 4, ec = fr;
#pragma unroll
    for (int mi = 0; mi < 4; ++mi)
#pragma unroll
        for (int ni = 0; ni < 4; ++ni)
#pragma unroll
            for (int r = 0; r < 4; ++r)
                sig[(size_t)(m0 + wm + mi * 16 + er + r) * NBS + (n0 + wn + ni * 16 + ec)]
                    = acc[mi][ni][r];
}

// ---------------------------------------------------------------------------
// K4: radial-return ep scan, scaled stress written back in place.
// depth-16 circular register prefetch.
// ---------------------------------------------------------------------------
__global__ __launch_bounds__(128) void k4_plast(float* __restrict__ sig)
{
    const int b = blockIdx.x;          // one batch per block
    const int p = threadIdx.x;         // 0..127 chain
    float* s = sig + (size_t)b * NT * NBS + 3 * p;

    float px[16], py[16], pz[16];
#pragma unroll
    for (int u = 0; u < 16; ++u) {
        const float* sp = s + (size_t)u * NBS;
        px[u] = sp[0]; py[u] = sp[1]; pz[u] = sp[2];
    }

    float ep = 0.0f;
#pragma unroll 16
    for (int t = 0; t < NT - 16; ++t) {
        const int sl = t & 15;
        float sxx = px[sl], syy = py[sl], txy = pz[sl];
        {
            const float* sp = s + (size_t)(t + 16) * NBS;
            px[sl] = sp[0]; py[sl] = sp[1]; pz[sl] = sp[2];
        }
        float seq = sqrtf(sxx*sxx - sxx*syy + syy*syy + 3.0f*txy*txy + 1e-12f);
        float fy = seq - (10.0f + 100.0f * ep);
        float dep = (fy > 0.0f) ? (fy / H3G) : 0.0f;
        ep += dep;
        float scale = (fy > 0.0f) ? ((10.0f + 100.0f * ep) / seq) : 1.0f;
        float* op = s + (size_t)t * NBS;
        op[0] = sxx * scale; op[1] = syy * scale; op[2] = txy * scale;
    }
#pragma unroll
    for (int t = NT - 16; t < NT; ++t) {
        const int sl = t & 15;
        float sxx = px[sl], syy = py[sl], txy = pz[sl];
        float seq = sqrtf(sxx*sxx - sxx*syy + syy*syy + 3.0f*txy*txy + 1e-12f);
        float fy = seq - (10.0f + 100.0f * ep);
        float dep = (fy > 0.0f) ? (fy / H3G) : 0.0f;
        ep += dep;
        float scale = (fy > 0.0f) ? ((10.0f + 100.0f * ep) / seq) : 1.0f;
        float* op = s + (size_t)t * NBS;
        op[0] = sxx * scale; op[1] = syy * scale; op[2] = txy * scale;
    }
}

// ---------------------------------------------------------------------------
// K5: out = softplus(sig @ W2^T). Row-per-thread, zero cross-lane ops.
// ---------------------------------------------------------------------------
__global__ __launch_bounds__(256) void k5_out(
    const float* __restrict__ sig, const float* __restrict__ W2,
    float* __restrict__ out)
{
    __shared__ float W2s[6][NBS];
    const int tid = threadIdx.x;
    for (int i = tid; i < 6 * NBS; i += 256) W2s[i / NBS][i % NBS] = W2[i];
    __syncthreads();

    const int row = blockIdx.x * 256 + tid;     // 512 blocks x 256 = NROWS
    const float4* sv = (const float4*)(sig + (size_t)row * NBS);

    float acc[6] = {0, 0, 0, 0, 0, 0};
#pragma unroll 8
    for (int q = 0; q < NBS / 4; ++q) {
        float4 v = sv[q];
#pragma unroll
        for (int o = 0; o < 6; ++o) {
            float4 wv = *(const float4*)&W2s[o][4 * q];
            acc[o] = fmaf(v.x, wv.x, acc[o]);
            acc[o] = fmaf(v.y, wv.y, acc[o]);
            acc[o] = fmaf(v.z, wv.z, acc[o]);
            acc[o] = fmaf(v.w, wv.w, acc[o]);
        }
    }

    float res[6];
#pragma unroll
    for (int o = 0; o < 6; ++o) {
        float z = acc[o];
        res[o] = fmaxf(z, 0.0f) + log1pf(expf(-fabsf(z)));
    }
    float* op = out + (size_t)row * 6;
#pragma unroll
    for (int o = 0; o < 6; ++o) op[o] = res[o];
}

// ---------------------------------------------------------------------------
extern "C" void kernel_launch(void* const* d_in, const int* in_sizes, int n_in,
                              void* d_out, int out_size, void* d_ws, size_t ws_size,
                              hipStream_t stream)
{
    const float* x   = (const float*)d_in[0];
    const float* W11 = (const float*)d_in[1];
    const float* b11 = (const float*)d_in[2];
    const float* W12 = (const float*)d_in[3];
    const float* W2  = (const float*)d_in[4];
    float* out = (float*)d_out;

    // ws layout: dnew [NROWS*64] fp32 (32MB) | sig [NROWS*384] fp32 (192MB)
    float* dnew = (float*)d_ws;
    float* sig  = (float*)((char*)d_ws + (size_t)NROWS * NCOH * sizeof(float));

    k0_w12<<<(NBS * NIN) / 256, 256, 0, stream>>>(W12);
    kx_split<<<(NROWS * 32) / 256, 256, 0, stream>>>(x);
    k1_fc11<<<NROWS / 128, 256, 0, stream>>>(x, W11, b11, dnew);
    k2_cummax<<<NB, 64, 0, stream>>>(dnew);
    k3_mfma<<<dim3(3, NROWS / 128), 256, 0, stream>>>(sig);
    k4_plast<<<NB, 128, 0, stream>>>(sig);
    k5_out<<<NROWS / 256, 256, 0, stream>>>(sig, W2, out);
}